// Round 1
// baseline (225.266 us; speedup 1.0000x reference)
//
#include <hip/hip_runtime.h>

#define N_NODES 50000
#define N_EDGES 800000
#define DMAX 64   // fixed CSR stride; max in-degree for this random graph ~35

// Build fixed-stride CSR of incoming edges per dst node.
__global__ __launch_bounds__(256) void fill_csr_k(const int* __restrict__ src,
                                                  const int* __restrict__ dst,
                                                  int* __restrict__ cnt,
                                                  int* __restrict__ csr) {
    int e = blockIdx.x * 256 + threadIdx.x;
    if (e >= N_EDGES) return;
    int s = src[e], d = dst[e];
    int slot = atomicAdd(&cnt[d], 1);
    if (slot < DMAX) csr[d * DMAX + slot] = s;
}

__global__ __launch_bounds__(256) void inv_k(const int* __restrict__ cnt,
                                             float* __restrict__ inv) {
    int n = blockIdx.x * 256 + threadIdx.x;
    if (n < N_NODES) inv[n] = rsqrtf((float)cnt[n] + 1.0f);  // +1 self-loop
}

// h[n][j] = sum_k x[n][k] * W[j][k] + b[j]   (W row-major [64][64])
__global__ __launch_bounds__(256) void lin64_k(const float* __restrict__ x,
                                               const float* __restrict__ W,
                                               const float* __restrict__ b,
                                               float* __restrict__ h) {
    __shared__ float Ws[64 * 68];  // row stride 68 floats = 272B (16B aligned, bank-spread)
    __shared__ float xs[4 * 68];
    int tid = threadIdx.x;
    int j = tid & 63, ln = tid >> 6;
    int n = blockIdx.x * 4 + ln;
#pragma unroll
    for (int t = 0; t < 16; ++t) {
        int idx = t * 256 + tid;             // coalesced read of W
        Ws[(idx >> 6) * 68 + (idx & 63)] = W[idx];
    }
    xs[ln * 68 + j] = x[n * 64 + j];
    __syncthreads();
    float acc = b[j];
    const float4* wp = (const float4*)&Ws[j * 68];
    const float4* xp = (const float4*)&xs[ln * 68];
#pragma unroll
    for (int k4 = 0; k4 < 16; ++k4) {
        float4 w = wp[k4];
        float4 xv = xp[k4];
        acc += w.x * xv.x + w.y * xv.y + w.z * xv.z + w.w * xv.w;
    }
    h[n * 64 + j] = acc;
}

// agg[n][d] = sum_{e: dst=n} h[src_e][d]*inv[src]*inv[n] + h[n][d]*inv[n]^2, optional ReLU
template <bool RELU>
__global__ __launch_bounds__(256) void gather64_k(const float* __restrict__ h,
                                                  const int* __restrict__ cnt,
                                                  const float* __restrict__ inv,
                                                  const int* __restrict__ csr,
                                                  float* __restrict__ out) {
    int tid = threadIdx.x;
    int lane = tid & 63, ln = tid >> 6;
    int n = blockIdx.x * 4 + ln;        // one wave per node
    int m = cnt[n];
    if (m > DMAX) m = DMAX;
    float invn = inv[n];
    int s_l = 0;
    float c_l = 0.f;
    if (lane < m) {
        s_l = csr[n * DMAX + lane];     // coalesced edge-list read
        c_l = inv[s_l];
    }
    float acc = h[n * 64 + lane] * invn * invn;  // self-loop term
    for (int i = 0; i < m; ++i) {
        int s = __shfl(s_l, i, 64);
        float c = __shfl(c_l, i, 64) * invn;
        acc += h[s * 64 + lane] * c;    // coalesced 256B row gather
    }
    if (RELU) acc = fmaxf(acc, 0.f);
    out[n * 64 + lane] = acc;
}

// h2[n] = dot(x[n,:], W2[0,:]) + b2
__global__ __launch_bounds__(256) void lin1_k(const float* __restrict__ x,
                                              const float* __restrict__ W2,
                                              const float* __restrict__ b2,
                                              float* __restrict__ h2) {
    int tid = threadIdx.x;
    int lane = tid & 63, ln = tid >> 6;
    int n = blockIdx.x * 4 + ln;
    float p = x[n * 64 + lane] * W2[lane];
#pragma unroll
    for (int off = 32; off; off >>= 1) p += __shfl_xor(p, off, 64);
    if (lane == 0) h2[n] = p + b2[0];
}

// out[n] = sum_{e: dst=n} h2[src]*inv[src]*inv[n] + h2[n]*inv[n]^2   (no relu)
__global__ __launch_bounds__(256) void gather1_k(const float* __restrict__ h2,
                                                 const int* __restrict__ cnt,
                                                 const float* __restrict__ inv,
                                                 const int* __restrict__ csr,
                                                 float* __restrict__ out) {
    int tid = threadIdx.x;
    int lane = tid & 63, ln = tid >> 6;
    int n = blockIdx.x * 4 + ln;
    int m = cnt[n];
    if (m > DMAX) m = DMAX;
    float invn = inv[n];
    float v = 0.f;
    if (lane < m) {
        int s = csr[n * DMAX + lane];
        v = h2[s] * inv[s];
    }
#pragma unroll
    for (int off = 32; off; off >>= 1) v += __shfl_xor(v, off, 64);
    if (lane == 0) out[n] = v * invn + h2[n] * invn * invn;
}

extern "C" void kernel_launch(void* const* d_in, const int* in_sizes, int n_in,
                              void* d_out, int out_size, void* d_ws, size_t ws_size,
                              hipStream_t stream) {
    const float* x  = (const float*)d_in[0];
    const int*   ei = (const int*)d_in[1];   // [2][E]: row 0 = src, row 1 = dst
    const float* W0 = (const float*)d_in[2];
    const float* b0 = (const float*)d_in[3];
    const float* W1 = (const float*)d_in[4];
    const float* b1 = (const float*)d_in[5];
    const float* W2 = (const float*)d_in[6];
    const float* b2 = (const float*)d_in[7];
    float* out = (float*)d_out;

    char* ws = (char*)d_ws;
    size_t off = 0;
    auto alloc = [&](size_t bytes) {
        void* p = ws + off;
        off = (off + bytes + 255) & ~(size_t)255;
        return p;
    };
    int*   cnt  = (int*)alloc((size_t)N_NODES * 4);
    float* inv  = (float*)alloc((size_t)N_NODES * 4);
    int*   csr  = (int*)alloc((size_t)N_NODES * DMAX * 4);
    float* bufH = (float*)alloc((size_t)N_NODES * 64 * 4);
    float* bufO = (float*)alloc((size_t)N_NODES * 64 * 4);
    float* bufX = (float*)alloc((size_t)N_NODES * 64 * 4);
    float* h2   = (float*)alloc((size_t)N_NODES * 4);
    // total ~52 MB

    const int* src = ei;
    const int* dst = ei + N_EDGES;

    hipMemsetAsync(cnt, 0, (size_t)N_NODES * 4, stream);
    fill_csr_k<<<(N_EDGES + 255) / 256, 256, 0, stream>>>(src, dst, cnt, csr);
    inv_k<<<(N_NODES + 255) / 256, 256, 0, stream>>>(cnt, inv);

    // layer 0
    lin64_k<<<N_NODES / 4, 256, 0, stream>>>(x, W0, b0, bufH);
    gather64_k<true><<<N_NODES / 4, 256, 0, stream>>>(bufH, cnt, inv, csr, bufO);
    // layer 1
    lin64_k<<<N_NODES / 4, 256, 0, stream>>>(bufO, W1, b1, bufH);
    gather64_k<true><<<N_NODES / 4, 256, 0, stream>>>(bufH, cnt, inv, csr, bufX);
    // layer 2 (D_OUT = 1)
    lin1_k<<<N_NODES / 4, 256, 0, stream>>>(bufX, W2, b2, h2);
    gather1_k<<<N_NODES / 4, 256, 0, stream>>>(h2, cnt, inv, csr, out);
}

// Round 2
// 157.051 us; speedup vs baseline: 1.4343x; 1.4343x over previous
//
#include <hip/hip_runtime.h>

#define N_NODES 50000
#define N_EDGES 800000
#define DMAX 64   // fixed CSR stride; max in-degree ~35 for Poisson(16) graph

// ---------------- CSR build ----------------
__global__ __launch_bounds__(256) void fill_csr_k(const int* __restrict__ src,
                                                  const int* __restrict__ dst,
                                                  int* __restrict__ cnt,
                                                  int* __restrict__ csr) {
    int e = blockIdx.x * 256 + threadIdx.x;
    if (e >= N_EDGES) return;
    int s = src[e], d = dst[e];
    int slot = atomicAdd(&cnt[d], 1);
    if (slot < DMAX) csr[d * DMAX + slot] = s;
}

__global__ __launch_bounds__(256) void inv_k(const int* __restrict__ cnt,
                                             float* __restrict__ inv) {
    int n = blockIdx.x * 256 + threadIdx.x;
    if (n < N_NODES) inv[n] = rsqrtf((float)cnt[n] + 1.0f);  // +1 self-loop
}

// ---------------- layer-0 linear: h0 = x @ W0^T + b0 ----------------
// 16 nodes/block, 4 accumulators/thread: 4x less W staging, 4x ILP.
__global__ __launch_bounds__(256) void lin0_k(const float* __restrict__ x,
                                              const float* __restrict__ W,
                                              const float* __restrict__ b,
                                              float* __restrict__ h) {
    __shared__ float Ws[64 * 68];   // row stride 68 floats (16B-aligned, bank-spread)
    __shared__ float xs[16 * 68];
    int tid = threadIdx.x;
    int j = tid & 63, ln = tid >> 6;
    int nb = blockIdx.x * 16;
    const float4* W4 = (const float4*)W;
#pragma unroll
    for (int i = 0; i < 4; ++i) {
        int idx4 = i * 256 + tid;                 // coalesced float4 read of W
        *(float4*)&Ws[(idx4 >> 4) * 68 + (idx4 & 15) * 4] = W4[idx4];
    }
    {
        const float4* x4 = (const float4*)(x + (size_t)nb * 64);
        float4 v = x4[tid];                       // 16 nodes x 64 feats = 256 float4
        *(float4*)&xs[(tid >> 4) * 68 + (tid & 15) * 4] = v;
    }
    __syncthreads();
    float a0 = b[j], a1 = b[j], a2 = b[j], a3 = b[j];
    const float4* wp  = (const float4*)&Ws[j * 68];
    const float4* xp0 = (const float4*)&xs[(ln * 4 + 0) * 68];
    const float4* xp1 = (const float4*)&xs[(ln * 4 + 1) * 68];
    const float4* xp2 = (const float4*)&xs[(ln * 4 + 2) * 68];
    const float4* xp3 = (const float4*)&xs[(ln * 4 + 3) * 68];
#pragma unroll
    for (int k4 = 0; k4 < 16; ++k4) {
        float4 w = wp[k4];
        float4 p0 = xp0[k4]; a0 += w.x*p0.x + w.y*p0.y + w.z*p0.z + w.w*p0.w;
        float4 p1 = xp1[k4]; a1 += w.x*p1.x + w.y*p1.y + w.z*p1.z + w.w*p1.w;
        float4 p2 = xp2[k4]; a2 += w.x*p2.x + w.y*p2.y + w.z*p2.z + w.w*p2.w;
        float4 p3 = xp3[k4]; a3 += w.x*p3.x + w.y*p3.y + w.z*p3.z + w.w*p3.w;
    }
    h[(size_t)(nb + ln * 4 + 0) * 64 + j] = a0;
    h[(size_t)(nb + ln * 4 + 1) * 64 + j] = a1;
    h[(size_t)(nb + ln * 4 + 2) * 64 + j] = a2;
    h[(size_t)(nb + ln * 4 + 3) * 64 + j] = a3;
}

// ------- fused: out = relu(gather(h)) @ W^T + b   (one wave per node) -------
__global__ __launch_bounds__(256) void gl_k(const float* __restrict__ h,
                                            const int* __restrict__ cnt,
                                            const float* __restrict__ inv,
                                            const int* __restrict__ csr,
                                            const float* __restrict__ W,
                                            const float* __restrict__ b,
                                            float* __restrict__ out) {
    __shared__ float Ws[64 * 68];
    __shared__ float rs[4 * 68];
    int tid = threadIdx.x;
    int j = tid & 63, ln = tid >> 6;
    int n = blockIdx.x * 4 + ln;

    // issue gather-side loads first so they're in flight during W staging
    int m = cnt[n];
    if (m > DMAX) m = DMAX;
    float invn = inv[n];
    int s_l = 0; float c_l = 0.f;
    if (j < m) {
        s_l = csr[n * DMAX + j];
        c_l = inv[s_l] * invn;
    }
    float acc = h[(size_t)n * 64 + j] * invn * invn;   // self-loop term

    const float4* W4 = (const float4*)W;
#pragma unroll
    for (int i = 0; i < 4; ++i) {
        int idx4 = i * 256 + tid;
        *(float4*)&Ws[(idx4 >> 4) * 68 + (idx4 & 15) * 4] = W4[idx4];
    }

    // edge gather, unrolled x4 for memory-level parallelism
    int i = 0;
    for (; i + 4 <= m; i += 4) {
        int s0 = __shfl(s_l, i, 64),   s1 = __shfl(s_l, i + 1, 64);
        int s2 = __shfl(s_l, i + 2, 64), s3 = __shfl(s_l, i + 3, 64);
        float c0 = __shfl(c_l, i, 64),   c1 = __shfl(c_l, i + 1, 64);
        float c2 = __shfl(c_l, i + 2, 64), c3 = __shfl(c_l, i + 3, 64);
        float v0 = h[(size_t)s0 * 64 + j];
        float v1 = h[(size_t)s1 * 64 + j];
        float v2 = h[(size_t)s2 * 64 + j];
        float v3 = h[(size_t)s3 * 64 + j];
        acc += v0 * c0; acc += v1 * c1; acc += v2 * c2; acc += v3 * c3;
    }
    for (; i < m; ++i) {
        int s = __shfl(s_l, i, 64);
        float c = __shfl(c_l, i, 64);
        acc += h[(size_t)s * 64 + j] * c;
    }

    rs[ln * 68 + j] = fmaxf(acc, 0.f);   // relu'd row, lane=feature
    __syncthreads();                      // covers Ws staging + rs

    // matvec: out[j] = sum_k rs[k] * W[j][k] + b[j]
    float o0 = b[j], o1 = 0.f;
    const float4* wp = (const float4*)&Ws[j * 68];
    const float4* rp = (const float4*)&rs[ln * 68];
#pragma unroll
    for (int k4 = 0; k4 < 16; k4 += 2) {
        float4 w0 = wp[k4],     r0 = rp[k4];
        float4 w1 = wp[k4 + 1], r1 = rp[k4 + 1];
        o0 += w0.x*r0.x + w0.y*r0.y + w0.z*r0.z + w0.w*r0.w;
        o1 += w1.x*r1.x + w1.y*r1.y + w1.z*r1.z + w1.w*r1.w;
    }
    out[(size_t)n * 64 + j] = o0 + o1;
}

// ------- fused: h2[n] = dot(relu(gather(h)), W2) + b2  (scalar out) -------
__global__ __launch_bounds__(256) void gd_k(const float* __restrict__ h,
                                            const int* __restrict__ cnt,
                                            const float* __restrict__ inv,
                                            const int* __restrict__ csr,
                                            const float* __restrict__ W2,
                                            const float* __restrict__ b2,
                                            float* __restrict__ h2) {
    int tid = threadIdx.x;
    int j = tid & 63, ln = tid >> 6;
    int n = blockIdx.x * 4 + ln;
    int m = cnt[n];
    if (m > DMAX) m = DMAX;
    float invn = inv[n];
    int s_l = 0; float c_l = 0.f;
    if (j < m) {
        s_l = csr[n * DMAX + j];
        c_l = inv[s_l] * invn;
    }
    float acc = h[(size_t)n * 64 + j] * invn * invn;
    int i = 0;
    for (; i + 4 <= m; i += 4) {
        int s0 = __shfl(s_l, i, 64),   s1 = __shfl(s_l, i + 1, 64);
        int s2 = __shfl(s_l, i + 2, 64), s3 = __shfl(s_l, i + 3, 64);
        float c0 = __shfl(c_l, i, 64),   c1 = __shfl(c_l, i + 1, 64);
        float c2 = __shfl(c_l, i + 2, 64), c3 = __shfl(c_l, i + 3, 64);
        float v0 = h[(size_t)s0 * 64 + j];
        float v1 = h[(size_t)s1 * 64 + j];
        float v2 = h[(size_t)s2 * 64 + j];
        float v3 = h[(size_t)s3 * 64 + j];
        acc += v0 * c0; acc += v1 * c1; acc += v2 * c2; acc += v3 * c3;
    }
    for (; i < m; ++i) {
        int s = __shfl(s_l, i, 64);
        float c = __shfl(c_l, i, 64);
        acc += h[(size_t)s * 64 + j] * c;
    }
    float p = fmaxf(acc, 0.f) * W2[j];
#pragma unroll
    for (int off = 32; off; off >>= 1) p += __shfl_xor(p, off, 64);
    if (j == 0) h2[n] = p + b2[0];
}

// ------- final scalar gather: out[n] = gather(h2) -------
__global__ __launch_bounds__(256) void gather1_k(const float* __restrict__ h2,
                                                 const int* __restrict__ cnt,
                                                 const float* __restrict__ inv,
                                                 const int* __restrict__ csr,
                                                 float* __restrict__ out) {
    int tid = threadIdx.x;
    int lane = tid & 63, ln = tid >> 6;
    int n = blockIdx.x * 4 + ln;
    int m = cnt[n];
    if (m > DMAX) m = DMAX;
    float invn = inv[n];
    float v = 0.f;
    if (lane < m) {
        int s = csr[n * DMAX + lane];
        v = h2[s] * inv[s];
    }
#pragma unroll
    for (int off = 32; off; off >>= 1) v += __shfl_xor(v, off, 64);
    if (lane == 0) out[n] = v * invn + h2[n] * invn * invn;
}

extern "C" void kernel_launch(void* const* d_in, const int* in_sizes, int n_in,
                              void* d_out, int out_size, void* d_ws, size_t ws_size,
                              hipStream_t stream) {
    const float* x  = (const float*)d_in[0];
    const int*   ei = (const int*)d_in[1];   // [2][E]: row 0 = src, row 1 = dst
    const float* W0 = (const float*)d_in[2];
    const float* b0 = (const float*)d_in[3];
    const float* W1 = (const float*)d_in[4];
    const float* b1 = (const float*)d_in[5];
    const float* W2 = (const float*)d_in[6];
    const float* b2 = (const float*)d_in[7];
    float* out = (float*)d_out;

    char* ws = (char*)d_ws;
    size_t off = 0;
    auto alloc = [&](size_t bytes) {
        void* p = ws + off;
        off = (off + bytes + 255) & ~(size_t)255;
        return p;
    };
    int*   cnt  = (int*)alloc((size_t)N_NODES * 4);
    float* inv  = (float*)alloc((size_t)N_NODES * 4);
    int*   csr  = (int*)alloc((size_t)N_NODES * DMAX * 4);
    float* bufA = (float*)alloc((size_t)N_NODES * 64 * 4);
    float* bufB = (float*)alloc((size_t)N_NODES * 64 * 4);
    float* h2   = (float*)alloc((size_t)N_NODES * 4);

    const int* src = ei;
    const int* dst = ei + N_EDGES;

    hipMemsetAsync(cnt, 0, (size_t)N_NODES * 4, stream);
    fill_csr_k<<<(N_EDGES + 255) / 256, 256, 0, stream>>>(src, dst, cnt, csr);
    inv_k<<<(N_NODES + 255) / 256, 256, 0, stream>>>(cnt, inv);

    // layer 0 linear
    lin0_k<<<N_NODES / 16, 256, 0, stream>>>(x, W0, b0, bufA);
    // gather + relu + layer-1 linear (fused)
    gl_k<<<N_NODES / 4, 256, 0, stream>>>(bufA, cnt, inv, csr, W1, b1, bufB);
    // gather + relu + layer-2 dot (fused)
    gd_k<<<N_NODES / 4, 256, 0, stream>>>(bufB, cnt, inv, csr, W2, b2, h2);
    // final scalar gather
    gather1_k<<<N_NODES / 4, 256, 0, stream>>>(h2, cnt, inv, csr, out);
}

// Round 3
// 147.469 us; speedup vs baseline: 1.5275x; 1.0650x over previous
//
#include <hip/hip_runtime.h>

#define N_NODES 50000
#define N_EDGES 800000
#define DMAX 64          // fixed CSR stride; max in-degree ~35 for Poisson(16)
#define PARTS 8          // = XCD count; relies on bid%8 -> XCD round-robin (perf-only)
#define NPP 6250         // nodes per partition (8*6250 = 50000)
#define FILL_BLKS 2048
#define LIN_BLKS 3125    // 50000/16
typedef unsigned short u16;

// ---- fat kernel: XCD-partitioned CSR fill (blocks 0..FILL_BLKS) + lin0 ----
__global__ __launch_bounds__(256) void fill_lin0_k(
    const int* __restrict__ src, const int* __restrict__ dst,
    int* __restrict__ cnt, u16* __restrict__ csr,
    const float* __restrict__ x, const float* __restrict__ W,
    const float* __restrict__ b, float* __restrict__ h)
{
    __shared__ float smem[64 * 68 + 16 * 68];
    int bid = blockIdx.x;
    int tid = threadIdx.x;
    if (bid < FILL_BLKS) {
        int part = bid & 7;                    // empirically the XCD id
        int lo = part * NPP, hi = lo + NPP;
        int t = (bid >> 3) * 256 + tid;        // 0..65535 within partition
        const int4* dst4 = (const int4*)dst;
        const int STRIDE = (FILL_BLKS / PARTS) * 256;   // 65536
        for (int q = t; q < N_EDGES / 4; q += STRIDE) {
            int4 d4 = dst4[q];
            int e = q * 4;
#define PROC(dd, ee)                                                   \
            if ((dd) >= lo && (dd) < hi) {                             \
                int s = src[ee];                                       \
                int slot = atomicAdd(&cnt[dd], 1);                     \
                if (slot < DMAX) csr[(size_t)(dd) * DMAX + slot] = (u16)s; \
            }
            PROC(d4.x, e) PROC(d4.y, e + 1) PROC(d4.z, e + 2) PROC(d4.w, e + 3)
#undef PROC
        }
    } else {
        // lin0: h = x @ W0^T + b0, 16 nodes/block, 4 accumulators/thread
        float* Ws = smem;             // [64][68]
        float* xs = smem + 64 * 68;   // [16][68]
        int j = tid & 63, ln = tid >> 6;
        int nb = (bid - FILL_BLKS) * 16;
        const float4* W4 = (const float4*)W;
#pragma unroll
        for (int i = 0; i < 4; ++i) {
            int idx4 = i * 256 + tid;
            *(float4*)&Ws[(idx4 >> 4) * 68 + (idx4 & 15) * 4] = W4[idx4];
        }
        {
            const float4* x4 = (const float4*)(x + (size_t)nb * 64);
            float4 v = x4[tid];
            *(float4*)&xs[(tid >> 4) * 68 + (tid & 15) * 4] = v;
        }
        __syncthreads();
        float a0 = b[j], a1 = a0, a2 = a0, a3 = a0;
        const float4* wp = (const float4*)&Ws[j * 68];
        const float4* p0 = (const float4*)&xs[(ln * 4 + 0) * 68];
        const float4* p1 = (const float4*)&xs[(ln * 4 + 1) * 68];
        const float4* p2 = (const float4*)&xs[(ln * 4 + 2) * 68];
        const float4* p3 = (const float4*)&xs[(ln * 4 + 3) * 68];
#pragma unroll
        for (int k4 = 0; k4 < 16; ++k4) {
            float4 w = wp[k4];
            float4 q0 = p0[k4]; a0 += w.x*q0.x + w.y*q0.y + w.z*q0.z + w.w*q0.w;
            float4 q1 = p1[k4]; a1 += w.x*q1.x + w.y*q1.y + w.z*q1.z + w.w*q1.w;
            float4 q2 = p2[k4]; a2 += w.x*q2.x + w.y*q2.y + w.z*q2.z + w.w*q2.w;
            float4 q3 = p3[k4]; a3 += w.x*q3.x + w.y*q3.y + w.z*q3.z + w.w*q3.w;
        }
        h[(size_t)(nb + ln * 4 + 0) * 64 + j] = a0;
        h[(size_t)(nb + ln * 4 + 1) * 64 + j] = a1;
        h[(size_t)(nb + ln * 4 + 2) * 64 + j] = a2;
        h[(size_t)(nb + ln * 4 + 3) * 64 + j] = a3;
    }
}

// ---- fused gather+relu+linear: out = relu(agg(h)) @ W^T + b ----
// 16 nodes/block (4 waves x 4 sequential nodes); W staged once per block.
__global__ __launch_bounds__(256) void gl_k(
    const float* __restrict__ h, const int* __restrict__ cnt,
    const u16* __restrict__ csr, const float* __restrict__ W,
    const float* __restrict__ b, float* __restrict__ out)
{
    __shared__ float Ws[64 * 68];
    __shared__ float rs[4][68];
    int tid = threadIdx.x, j = tid & 63, w = tid >> 6;
    int nb = blockIdx.x * 16;
    const float4* W4 = (const float4*)W;
#pragma unroll
    for (int i = 0; i < 4; ++i) {
        int idx4 = i * 256 + tid;
        *(float4*)&Ws[(idx4 >> 4) * 68 + (idx4 & 15) * 4] = W4[idx4];
    }
    __syncthreads();
    const float4* wp = (const float4*)&Ws[j * 68];
    float bj = b[j];
#pragma unroll 1
    for (int t = 0; t < 4; ++t) {
        int n = nb + w * 4 + t;
        int mf = cnt[n];
        int m = min(mf, DMAX);
        float invn = rsqrtf((float)mf + 1.f);
        int s_l = 0; float c_l = 0.f;
        if (j < m) {
            s_l = (int)csr[(size_t)n * DMAX + j];
            c_l = rsqrtf((float)cnt[s_l] + 1.f) * invn;
        }
        float acc = h[(size_t)n * 64 + j] * (invn * invn);
        int i = 0;
        for (; i + 8 <= m; i += 8) {
            int s0=__shfl(s_l,i,64),   s1=__shfl(s_l,i+1,64);
            int s2=__shfl(s_l,i+2,64), s3=__shfl(s_l,i+3,64);
            int s4=__shfl(s_l,i+4,64), s5=__shfl(s_l,i+5,64);
            int s6=__shfl(s_l,i+6,64), s7=__shfl(s_l,i+7,64);
            float c0=__shfl(c_l,i,64),   c1=__shfl(c_l,i+1,64);
            float c2=__shfl(c_l,i+2,64), c3=__shfl(c_l,i+3,64);
            float c4=__shfl(c_l,i+4,64), c5=__shfl(c_l,i+5,64);
            float c6=__shfl(c_l,i+6,64), c7=__shfl(c_l,i+7,64);
            float v0=h[(size_t)s0*64+j], v1=h[(size_t)s1*64+j];
            float v2=h[(size_t)s2*64+j], v3=h[(size_t)s3*64+j];
            float v4=h[(size_t)s4*64+j], v5=h[(size_t)s5*64+j];
            float v6=h[(size_t)s6*64+j], v7=h[(size_t)s7*64+j];
            acc += v0*c0; acc += v1*c1; acc += v2*c2; acc += v3*c3;
            acc += v4*c4; acc += v5*c5; acc += v6*c6; acc += v7*c7;
        }
        for (; i < m; ++i) {
            int s = __shfl(s_l, i, 64);
            float c = __shfl(c_l, i, 64);
            acc += h[(size_t)s * 64 + j] * c;
        }
        rs[w][j] = fmaxf(acc, 0.f);       // wave-private LDS slice
        __builtin_amdgcn_wave_barrier();  // keep compiler from reordering
        float o = bj;
        const float4* rp = (const float4*)&rs[w][0];
#pragma unroll
        for (int k4 = 0; k4 < 16; ++k4) {
            float4 wv = wp[k4]; float4 rv = rp[k4];
            o += wv.x*rv.x + wv.y*rv.y + wv.z*rv.z + wv.w*rv.w;
        }
        __builtin_amdgcn_wave_barrier();
        out[(size_t)n * 64 + j] = o;
    }
}

// ---- fused gather+relu+dot: h2[n] = dot(relu(agg(h)), W2) + b2 ----
__global__ __launch_bounds__(256) void gd_k(
    const float* __restrict__ h, const int* __restrict__ cnt,
    const u16* __restrict__ csr, const float* __restrict__ W2,
    const float* __restrict__ b2, float* __restrict__ h2)
{
    int tid = threadIdx.x, j = tid & 63, w = tid >> 6;
    int nb = blockIdx.x * 16;
    float w2 = W2[j], b2s = b2[0];
#pragma unroll 1
    for (int t = 0; t < 4; ++t) {
        int n = nb + w * 4 + t;
        int mf = cnt[n];
        int m = min(mf, DMAX);
        float invn = rsqrtf((float)mf + 1.f);
        int s_l = 0; float c_l = 0.f;
        if (j < m) {
            s_l = (int)csr[(size_t)n * DMAX + j];
            c_l = rsqrtf((float)cnt[s_l] + 1.f) * invn;
        }
        float acc = h[(size_t)n * 64 + j] * (invn * invn);
        int i = 0;
        for (; i + 8 <= m; i += 8) {
            int s0=__shfl(s_l,i,64),   s1=__shfl(s_l,i+1,64);
            int s2=__shfl(s_l,i+2,64), s3=__shfl(s_l,i+3,64);
            int s4=__shfl(s_l,i+4,64), s5=__shfl(s_l,i+5,64);
            int s6=__shfl(s_l,i+6,64), s7=__shfl(s_l,i+7,64);
            float c0=__shfl(c_l,i,64),   c1=__shfl(c_l,i+1,64);
            float c2=__shfl(c_l,i+2,64), c3=__shfl(c_l,i+3,64);
            float c4=__shfl(c_l,i+4,64), c5=__shfl(c_l,i+5,64);
            float c6=__shfl(c_l,i+6,64), c7=__shfl(c_l,i+7,64);
            float v0=h[(size_t)s0*64+j], v1=h[(size_t)s1*64+j];
            float v2=h[(size_t)s2*64+j], v3=h[(size_t)s3*64+j];
            float v4=h[(size_t)s4*64+j], v5=h[(size_t)s5*64+j];
            float v6=h[(size_t)s6*64+j], v7=h[(size_t)s7*64+j];
            acc += v0*c0; acc += v1*c1; acc += v2*c2; acc += v3*c3;
            acc += v4*c4; acc += v5*c5; acc += v6*c6; acc += v7*c7;
        }
        for (; i < m; ++i) {
            int s = __shfl(s_l, i, 64);
            float c = __shfl(c_l, i, 64);
            acc += h[(size_t)s * 64 + j] * c;
        }
        float p = fmaxf(acc, 0.f) * w2;
#pragma unroll
        for (int off = 32; off; off >>= 1) p += __shfl_xor(p, off, 64);
        if (j == 0) h2[n] = p + b2s;
    }
}

// ---- final scalar gather: out[n] = agg(h2)[n] ----
__global__ __launch_bounds__(256) void gather1_k(
    const float* __restrict__ h2, const int* __restrict__ cnt,
    const u16* __restrict__ csr, float* __restrict__ out)
{
    int tid = threadIdx.x, j = tid & 63, w = tid >> 6;
    int nb = blockIdx.x * 16;
#pragma unroll 1
    for (int t = 0; t < 4; ++t) {
        int n = nb + w * 4 + t;
        int mf = cnt[n];
        int m = min(mf, DMAX);
        float invn = rsqrtf((float)mf + 1.f);
        float v = 0.f;
        if (j < m) {
            int s = (int)csr[(size_t)n * DMAX + j];
            v = h2[s] * rsqrtf((float)cnt[s] + 1.f);
        }
#pragma unroll
        for (int off = 32; off; off >>= 1) v += __shfl_xor(v, off, 64);
        if (j == 0) out[n] = v * invn + h2[n] * invn * invn;
    }
}

extern "C" void kernel_launch(void* const* d_in, const int* in_sizes, int n_in,
                              void* d_out, int out_size, void* d_ws, size_t ws_size,
                              hipStream_t stream) {
    const float* x  = (const float*)d_in[0];
    const int*   ei = (const int*)d_in[1];   // [2][E]: row 0 = src, row 1 = dst
    const float* W0 = (const float*)d_in[2];
    const float* b0 = (const float*)d_in[3];
    const float* W1 = (const float*)d_in[4];
    const float* b1 = (const float*)d_in[5];
    const float* W2 = (const float*)d_in[6];
    const float* b2 = (const float*)d_in[7];
    float* out = (float*)d_out;

    char* ws = (char*)d_ws;
    size_t off = 0;
    auto alloc = [&](size_t bytes) {
        void* p = ws + off;
        off = (off + bytes + 255) & ~(size_t)255;
        return p;
    };
    int*   cnt  = (int*)alloc((size_t)N_NODES * 4);
    u16*   csr  = (u16*)alloc((size_t)N_NODES * DMAX * 2);
    float* bufA = (float*)alloc((size_t)N_NODES * 64 * 4);
    float* bufB = (float*)alloc((size_t)N_NODES * 64 * 4);
    float* h2   = (float*)alloc((size_t)N_NODES * 4);

    const int* src = ei;
    const int* dst = ei + N_EDGES;

    hipMemsetAsync(cnt, 0, (size_t)N_NODES * 4, stream);
    // CSR fill (XCD-partitioned) + layer-0 linear, concurrent in one launch
    fill_lin0_k<<<FILL_BLKS + LIN_BLKS, 256, 0, stream>>>(src, dst, cnt, csr,
                                                          x, W0, b0, bufA);
    // gather + relu + layer-1 linear
    gl_k<<<LIN_BLKS, 256, 0, stream>>>(bufA, cnt, csr, W1, b1, bufB);
    // gather + relu + layer-2 dot
    gd_k<<<LIN_BLKS, 256, 0, stream>>>(bufB, cnt, csr, W2, b2, h2);
    // final scalar gather
    gather1_k<<<LIN_BLKS, 256, 0, stream>>>(h2, cnt, csr, out);
}